// Round 10
// baseline (228.623 us; speedup 1.0000x reference)
//
#include <hip/hip_runtime.h>
#include <math.h>

#define CCH 128
#define HH 64
#define WW 64
#define SHD 17
#define NSHIFT (SHD*SHD)   // 289

// ---- workspace layout ----
// float-index offsets:
#define OFF_NORM   0                         // 16 f   grd sumsq (k_scale writes)
#define OFF_NPART  16                        // 512*16 f grd-norm partials [(h*8+csl)][n]
#define OFF_EPART  8208                      // 8*65536 f energy partials [csl][(n*64+h)*64+w]
#define OFF_SCALE  532496                    // 16*289 f
#define OFF_SIM    537120                    // 289*256 f raw sim sums [s][m*16+n]
// byte offsets:
#define OFF_SATP_B 2444416                   // padded sat bf16: 8 x [h64][slot80][n16][c16]
#define SATP_SLICE_U16 (64*80*16*16)         // 1310720
#define OFF_GRDB_B (OFF_SATP_B + 8*SATP_SLICE_U16*2)   // 23415936
#define GRD_SLICE_U16 (64*64*16*16)          // 1048576
#define OFF_PART_B (OFF_GRDB_B + 8*GRD_SLICE_U16*2)    // 40193152
#define NBLK_CORR 1088                       // csl8 (low bits) x dyi17 x hq8
// part: per block 17 x 64 x 4 floats = 4352 f (17.4 KB); total 18.9 MB

typedef __bf16 bf16x8 __attribute__((ext_vector_type(8)));
typedef float floatx4 __attribute__((ext_vector_type(4)));
typedef unsigned short ushort8 __attribute__((ext_vector_type(8)));

#define AS1 __attribute__((address_space(1)))
#define AS3 __attribute__((address_space(3)))

__device__ inline unsigned short f2bf(float f) {
    unsigned x = __float_as_uint(f);
    unsigned r = x + 0x7FFFu + ((x >> 16) & 1u);   // RNE
    return (unsigned short)(r >> 16);
}

// ---------------- K1: convert + transpose + norm/energy partials ----------
// grid: 1024 = tensor2 x h64 x csl8.  No atomics, no pre-zero needed.
// LDS tile written as ds_write_b128 (register-buffered bf16), not scalar u16.
__global__ __launch_bounds__(256) void k_prep(const float* __restrict__ sat,
                                              const float* __restrict__ grd,
                                              float* __restrict__ ws) {
    __shared__ unsigned short tile[64 * 256];   // 32 KB: [w][ (n+w)&15 ][c16]
    __shared__ float nred[16];
    int b = blockIdx.x;
    int tensor = b >> 9, h = (b >> 3) & 63, csl = b & 7;
    const float* src = tensor ? grd : sat;
    unsigned short* dstS = (unsigned short*)((char*)ws + OFF_SATP_B);
    unsigned short* dstG = (unsigned short*)((char*)ws + OFF_GRDB_B);
    int t = threadIdx.x;
    int n = t >> 4, wq = t & 15;
    int w0 = wq * 4;

    float en0 = 0.f, en1 = 0.f, en2 = 0.f, en3 = 0.f;
    ushort8 pk[4][2];
    const float* base = src + ((size_t)(n * CCH + csl * 16) * 4096) + h * 64 + w0;
    #pragma unroll
    for (int c = 0; c < 16; ++c) {
        float4 v = *(const float4*)(base + (size_t)c * 4096);
        en0 = fmaf(v.x, v.x, en0); en1 = fmaf(v.y, v.y, en1);
        en2 = fmaf(v.z, v.z, en2); en3 = fmaf(v.w, v.w, en3);
        int c8 = c >> 3, ci = c & 7;
        pk[0][c8][ci] = f2bf(v.x); pk[1][c8][ci] = f2bf(v.y);
        pk[2][c8][ci] = f2bf(v.z); pk[3][c8][ci] = f2bf(v.w);
    }
    #pragma unroll
    for (int wi = 0; wi < 4; ++wi) {
        int w = w0 + wi, slot = (n + w) & 15;
        *(ushort8*)&tile[w * 256 + slot * 16 + 0] = pk[wi][0];
        *(ushort8*)&tile[w * 256 + slot * 16 + 8] = pk[wi][1];
    }

    if (tensor == 0) {
        float* eg = ws + OFF_EPART + (size_t)csl * 65536 + ((size_t)n * 64 + h) * 64 + w0;
        *(float4*)eg = make_float4(en0, en1, en2, en3);   // plain partial store
    } else {
        float s = en0 + en1 + en2 + en3;
        #pragma unroll
        for (int off = 8; off; off >>= 1) s += __shfl_xor(s, off);  // 16-lane group
        if (wq == 0) nred[n] = s;
    }

    __syncthreads();
    if (tensor == 1 && t < 16)
        ws[OFF_NPART + (size_t)(h * 8 + csl) * 16 + t] = nred[t];

    unsigned short* dst = tensor
        ? dstG + (size_t)csl * GRD_SLICE_U16 + (size_t)h * 16384
        : dstS + (size_t)csl * SATP_SLICE_U16 + ((size_t)h * 80 + 8) * 256;
    #pragma unroll
    for (int i = 0; i < 8; ++i) {
        int o = i * 256 + t;
        int w = o >> 5, nn = (o >> 1) & 15, c8 = o & 1;
        ushort8 val = *(ushort8*)&tile[w * 256 + ((nn + w) & 15) * 16 + c8 * 8];
        *(ushort8*)&dst[(size_t)o * 8] = val;
    }
    if (tensor == 0) {
        ushort8 z = (ushort8)0;
        #pragma unroll
        for (int i = 0; i < 2; ++i) {
            int o = i * 256 + t;
            int slot = o >> 5, wi = o & 31;
            int ps = slot < 8 ? slot : slot + 64;
            *(ushort8*)&dstS[(size_t)csl * SATP_SLICE_U16 +
                             ((size_t)h * 80 + ps) * 256 + wi * 8] = z;
        }
    }
}

// ---------------- K2: energy -> windowed scale; also grd norms ------------
__global__ __launch_bounds__(320) void k_scale(float* __restrict__ ws) {
    __shared__ float E[64 * 64];
    __shared__ float R[64 * 17];
    int m = blockIdx.x;
    int t = threadIdx.x;
    float* scale = ws + OFF_SCALE + (size_t)m * NSHIFT;

    // grd norm m: wave 0 sums 512 partials (8 per lane) + butterfly
    if (t < 64) {
        float s = 0.f;
        const float* np = ws + OFF_NPART + m;
        #pragma unroll
        for (int j = 0; j < 8; ++j) s += np[(size_t)(j * 64 + t) * 16];
        #pragma unroll
        for (int off = 32; off; off >>= 1) s += __shfl_xor(s, off);
        if (t == 0) ws[OFF_NORM + m] = s;
    }

    const float* ep = ws + OFF_EPART + (size_t)m * 4096;
    for (int i = t; i < 4096; i += 320) {
        float s = 0.f;
        #pragma unroll
        for (int csl = 0; csl < 8; ++csl) s += ep[(size_t)csl * 65536 + i];
        E[i] = s;
    }
    __syncthreads();
    for (int i = t; i < 64 * 17; i += 320) {
        int y = i / 17, j = i % 17;
        int x0 = max(0, j - 8), x1 = min(64, j + 56);
        float s = 0.f;
        for (int x = x0; x < x1; ++x) s += E[y * 64 + x];
        R[i] = s;
    }
    __syncthreads();
    for (int idx = t; idx < NSHIFT; idx += 320) {
        int ii = idx / 17, j = idx % 17;
        int y0 = max(0, ii - 8), y1 = min(64, ii + 56);
        float s = 0.f;
        for (int y = y0; y < y1; ++y) s += R[y * 17 + j];
        scale[idx] = 1.f / fmaxf(sqrtf(s), 1e-12f);
    }
}

// ---------------- K3: MFMA cross-correlation ----------------
// Main loop identical to R9 (47.6% MfmaUtil). Epilogue: plain-write LDS
// cross-wave reduce (no atomics), 4-way dxi split, one 17.4 KB partial/block.
__global__ __launch_bounds__(256, 2) void k_corr(const unsigned short* __restrict__ satp,
                                                 const unsigned short* __restrict__ grdb,
                                                 float* __restrict__ part) {
    __shared__ alignas(16) unsigned char smem[81920];
    int b = blockIdx.x;
    int csl = b & 7;
    int r2  = b >> 3;
    int dyi = r2 % 17;
    int hq  = r2 / 17;             // 0..7
    int h0  = hq * 8;
    int t = threadIdx.x;
    int wv = t >> 6, l = t & 63;
    int m16 = l & 15, q = l >> 4, jl = q >> 1, c8 = q & 1;
    int wbase = wv * 16;

    const unsigned short* sats = satp + (size_t)csl * SATP_SLICE_U16;
    const unsigned short* grds = grdb + (size_t)csl * GRD_SLICE_U16;
    const unsigned short* goff = grds + ((wbase + jl) * 16 + m16) * 16 + c8 * 8;
    int hl = max(0, 8 - dyi - h0), hu = min(8, 72 - dyi - h0);

    floatx4 acc[17];
    #pragma unroll
    for (int d = 0; d < 17; ++d) acc[d] = (floatx4)0.f;

    #define STAGE(hs, p)                                                            \
        do {                                                                        \
            _Pragma("unroll")                                                       \
            for (int i_ = 0; i_ < 10; ++i_) {                                       \
                const unsigned short* g_ = sats + (size_t)(hs) * 20480              \
                                         + wv * 5120 + i_ * 512 + l * 8;            \
                __builtin_amdgcn_global_load_lds((AS1 void*)(unsigned short*)g_,    \
                    (AS3 void*)(smem + (p) * 40960 + wv * 10240 + i_ * 1024 + l * 16), \
                    16, 0, 0);                                                      \
            }                                                                       \
        } while (0)

    if (hl < hu) {
        int hs0 = h0 + hl + dyi - 8;
        STAGE(hs0, 0);
        bf16x8 Bc[8], Bn[8];
        #pragma unroll
        for (int bi = 0; bi < 8; ++bi)
            Bc[bi] = *(const bf16x8*)(goff + (size_t)(h0 + hl) * 16384 + bi * 512);

        for (int hh = hl; hh < hu; ++hh) {
            __syncthreads();                     // staged buf[hh&1] ready
            int p = (hh - hl) & 1;
            if (hh + 1 < hu) {
                STAGE(hs0 + (hh - hl) + 1, p ^ 1);
                #pragma unroll
                for (int bi = 0; bi < 8; ++bi)
                    Bn[bi] = *(const bf16x8*)(goff + (size_t)(h0 + hh + 1) * 16384 + bi * 512);
            }
            const unsigned char* aptr = smem + p * 40960 + jl * 512 + m16 * 32 + c8 * 16;
            bf16x8 A = *(const bf16x8*)(aptr + wbase * 512);
            #pragma unroll
            for (int wo = 0; wo < 31; ++wo) {    // slot = wbase + wo (+jl)
                bf16x8 An = A;
                if (wo < 30) An = *(const bf16x8*)(aptr + (wbase + wo + 1) * 512);
                #pragma unroll
                for (int bi = 0; bi < 8; ++bi) {
                    int dxi = wo - 2 * bi;       // compile-time after unroll
                    if (dxi >= 0 && dxi <= 16)
                        acc[dxi] = __builtin_amdgcn_mfma_f32_16x16x32_bf16(A, Bc[bi], acc[dxi], 0, 0, 0);
                }
                A = An;
            }
            #pragma unroll
            for (int bi = 0; bi < 8; ++bi) Bc[bi] = Bn[bi];
        }
    }
    #undef STAGE

    // cross-wave reduce: plain LDS writes (region per wave), 4-way dxi split
    __syncthreads();                         // staging reads done
    float* red = (float*)smem;               // 4 x 17 x 64 x floatx4 = 69632 B
    #pragma unroll
    for (int dxi = 0; dxi < 17; ++dxi)
        *(floatx4*)&red[(((wv * 17 + dxi) * 64) + l) * 4] = acc[dxi];
    __syncthreads();
    float* pb = part + (size_t)b * 4352;     // [dxi][l][r]
    for (int dxi = wv; dxi < 17; dxi += 4) {
        floatx4 s = *(floatx4*)&red[((0 * 17 + dxi) * 64 + l) * 4];
        s += *(floatx4*)&red[((1 * 17 + dxi) * 64 + l) * 4];
        s += *(floatx4*)&red[((2 * 17 + dxi) * 64 + l) * 4];
        s += *(floatx4*)&red[((3 * 17 + dxi) * 64 + l) * 4];
        *(floatx4*)&pb[(dxi * 64 + l) * 4] = s;
    }
}

// ---------------- K4: sum partials -> simmat (no atomics) -----------------
__global__ void k_reduce(const float* __restrict__ part, float* __restrict__ ws) {
    int b = blockIdx.x;            // 289 = dyi*17+dxi
    int dyi = b / 17, dxi = b % 17;
    int l = threadIdx.x;           // 64
    floatx4 s4 = (floatx4)0.f;
    for (int hq = 0; hq < 8; ++hq) {
        #pragma unroll
        for (int csl = 0; csl < 8; ++csl) {
            int blk = ((hq * 17 + dyi) << 3) | csl;
            s4 += *(const floatx4*)&part[((size_t)blk * 17 + dxi) * 256 + l * 4];
        }
    }
    int n = l & 15, q = l >> 4;
    float* sm = ws + OFF_SIM + (size_t)b * 256;
    #pragma unroll
    for (int r = 0; r < 4; ++r)
        sm[(q * 4 + r) * 16 + n] = s4[r];
}

// ---------------- K5: epilogue -> 3 scalars ----------------
__global__ void k_final(const float* __restrict__ ws, float* __restrict__ out) {
    __shared__ float dist_s[256];
    __shared__ float pos_s[16];
    __shared__ float red[256];
    __shared__ float minv[16];
    int t = threadIdx.x;          // t = m*16 + n
    int m = t >> 4, n = t & 15;

    const float* sim = ws + OFF_SIM;
    const float* sc  = ws + OFF_SCALE + (size_t)m * NSHIFT;
    float best = -1e30f;
    for (int s = 0; s < NSHIFT; ++s)
        best = fmaxf(best, sim[(size_t)s * 256 + t] * sc[s]);
    float Ng  = sqrtf(ws[OFF_NORM + n]);
    float simv = best / fmaxf(Ng, 1e-12f);
    float d   = 2.f - 2.f * simv;
    dist_s[t] = d;
    if (m == n) pos_s[m] = d;
    __syncthreads();

    float x1 = (pos_s[n] - d) * 10.f;
    float x2 = (pos_s[m] - d) * 10.f;
    float sp1 = x1 > 20.f ? x1 : log1pf(expf(x1));
    float sp2 = x2 > 20.f ? x2 : log1pf(expf(x2));
    red[t] = sp1 + sp2;
    __syncthreads();
    for (int off = 128; off; off >>= 1) {
        if (t < off) red[t] += red[t + off];
        __syncthreads();
    }
    if (t < 16) {
        float mv = 1e30f;
        for (int nn = 0; nn < 16; ++nn) mv = fminf(mv, dist_s[t * 16 + nn]);
        minv[t] = mv;
    }
    __syncthreads();
    if (t == 0) {
        float psum = 0.f, msum = 0.f;
        for (int qq = 0; qq < 16; ++qq) { psum += pos_s[qq]; msum += minv[qq]; }
        out[0] = red[0] / 48.f;
        out[1] = psum / 16.f;
        out[2] = msum / 16.f;
    }
}

extern "C" void kernel_launch(void* const* d_in, const int* in_sizes, int n_in,
                              void* d_out, int out_size, void* d_ws, size_t ws_size,
                              hipStream_t stream) {
    const float* sat = (const float*)d_in[0];
    const float* grd = (const float*)d_in[1];
    float* out = (float*)d_out;
    float* ws  = (float*)d_ws;
    const unsigned short* satp = (const unsigned short*)((char*)d_ws + OFF_SATP_B);
    const unsigned short* grdb = (const unsigned short*)((char*)d_ws + OFF_GRDB_B);
    float* part = (float*)((char*)d_ws + OFF_PART_B);

    k_prep  <<<1024,      256, 0, stream>>>(sat, grd, ws);
    k_scale <<<16,        320, 0, stream>>>(ws);
    k_corr  <<<NBLK_CORR, 256, 0, stream>>>(satp, grdb, part);
    k_reduce<<<NSHIFT,     64, 0, stream>>>(part, ws);
    k_final <<<1,         256, 0, stream>>>(ws, out);
}